// Round 1
// baseline (60.695 us; speedup 1.0000x reference)
//
#include <hip/hip_runtime.h>
#include <math.h>

namespace {

constexpr int NSC  = 512;   // subcarriers
constexpr int CP   = 7;     // cyclic prefix
constexpr int NTOT = 519;   // N + CP

__device__ __forceinline__ float2 cmulf(float2 a, float2 b) {
    return make_float2(a.x * b.x - a.y * b.y, a.x * b.y + a.y * b.x);
}

struct cd { double x, y; };
__device__ __forceinline__ cd cmuld(cd a, cd b) { return {a.x*b.x - a.y*b.y, a.x*b.y + a.y*b.x}; }
__device__ __forceinline__ cd csubd(cd a, cd b) { return {a.x - b.x, a.y - b.y}; }
__device__ __forceinline__ cd cdivd(cd a, cd b) {
    double d = b.x*b.x + b.y*b.y;
    return {(a.x*b.x + a.y*b.y) / d, (a.y*b.x - a.x*b.y) / d};
}

__global__ __launch_bounds__(512) void ofdm_mimo_kernel(
    const float* __restrict__ y_data,
    const float* __restrict__ y_ls,
    const int*   __restrict__ x_idx,
    float*       __restrict__ out,
    int B)
{
    __shared__ float2 buf[4][NSC];        // 0: data r0, 1: data r1, 2: ls r0, 3: ls r1
    __shared__ float2 tw[NSC / 2];        // exp(-2*pi*i*m/512)
    __shared__ float2 pil[2][2][NSC / 2]; // [tx][rx][pilot]

    const int b   = blockIdx.x;
    const int tid = threadIdx.x;

    const float data_scale = 1.0f / 512.0f;
    const float ls_scale   = (float)(1.0 / (512.0 * 0.22627416997969522)); // 1/(N*sqrt(pi_p))

    // ---- load CP-stripped samples, bit-reversed, with scale folded in ----
    #pragma unroll
    for (int e = tid; e < 4 * NSC; e += 512) {
        int q = e >> 9;          // which of the 4 signals
        int i = e & (NSC - 1);   // time index within the 512-sample window
        int r = q & 1;
        const float* src = (q < 2) ? y_data : y_ls;
        float sc = (q < 2) ? data_scale : ls_scale;
        size_t off = ((size_t)(b * 2 + r) * NTOT + CP + i) * 2;
        float re = src[off]     * sc;
        float im = src[off + 1] * sc;
        int rev = (int)(__brev((unsigned)i) >> 23);   // 9-bit reversal
        buf[q][rev] = make_float2(re, im);
    }
    if (tid < 256) {
        double ang = -2.0 * M_PI * (double)tid / 512.0;
        tw[tid] = make_float2((float)cos(ang), (float)sin(ang));
    }
    __syncthreads();

    // ---- 9 radix-2 DIT stages, 4 FFTs concurrently ----
    for (int s = 0; s < 9; ++s) {
        int half = 1 << s;
        #pragma unroll
        for (int j2 = tid; j2 < 1024; j2 += 512) {
            int q  = j2 >> 8;        // FFT id
            int jj = j2 & 255;       // butterfly id within FFT
            int g  = jj >> s;        // group
            int k  = jj & (half - 1);
            int i0 = (g << (s + 1)) + k;
            int i1 = i0 + half;
            float2 w = tw[k << (8 - s)];
            float2 a = buf[q][i0];
            float2 t = cmulf(w, buf[q][i1]);
            buf[q][i0] = make_float2(a.x + t.x, a.y + t.y);
            buf[q][i1] = make_float2(a.x - t.x, a.y - t.y);
        }
        __syncthreads();
    }

    // ---- comb pilot LS estimates: pil[t][r][k] = Y_l[r][t+2k] / x_ls[t][t+2k] ----
    const float lev[4] = {-0.9486832980505138f, -0.31622776601683794f,
                           0.31622776601683794f, 0.9486832980505138f};
    #pragma unroll
    for (int p = tid; p < 1024; p += 512) {
        int t = p >> 9;
        int r = (p >> 8) & 1;
        int k = p & 255;
        int comb = t + 2 * k;
        int idx = x_idx[((size_t)b * 2 + t) * NSC + comb];
        float xr = lev[idx & 3];
        float xi = lev[(idx >> 2) & 3];
        float2 yl = buf[2 + r][comb];
        float inv = 1.0f / (xr * xr + xi * xi);
        pil[t][r][k] = make_float2((yl.x * xr + yl.y * xi) * inv,
                                   (yl.y * xr - yl.x * xi) * inv);
    }
    __syncthreads();

    // ---- per-subcarrier: interp H, 2x2 solve (fp64 Cramer), demap ----
    {
        const int n = tid;
        cd H[2][2];
        #pragma unroll
        for (int r = 0; r < 2; ++r) {
            // t = 0: pilots at even n (plus copy at n=511)
            float2 h0;
            if ((n & 1) == 0) {
                h0 = pil[0][r][n >> 1];
            } else if (n == NSC - 1) {
                h0 = pil[0][r][255];
            } else {
                float2 a = pil[0][r][n >> 1];
                float2 c = pil[0][r][(n >> 1) + 1];
                h0 = make_float2(0.5f * (a.x + c.x), 0.5f * (a.y + c.y));
            }
            // t = 1: pilots at odd n (plus copy at n=0)
            float2 h1;
            if (n & 1) {
                h1 = pil[1][r][n >> 1];
            } else if (n == 0) {
                h1 = pil[1][r][0];
            } else {
                float2 a = pil[1][r][(n >> 1) - 1];
                float2 c = pil[1][r][n >> 1];
                h1 = make_float2(0.5f * (a.x + c.x), 0.5f * (a.y + c.y));
            }
            H[r][0] = {(double)h0.x, (double)h0.y};
            H[r][1] = {(double)h1.x, (double)h1.y};
        }
        float2 y0f = buf[0][n];
        float2 y1f = buf[1][n];
        cd Y0 = {(double)y0f.x, (double)y0f.y};
        cd Y1 = {(double)y1f.x, (double)y1f.y};

        cd det = csubd(cmuld(H[0][0], H[1][1]), cmuld(H[0][1], H[1][0]));
        cd X0  = cdivd(csubd(cmuld(H[1][1], Y0), cmuld(H[0][1], Y1)), det);
        cd X1  = cdivd(csubd(cmuld(H[0][0], Y1), cmuld(H[1][0], Y0)), det);
        const double inv_sqrt_pi = 1.0 / 0.22627416997969522;
        X0.x *= inv_sqrt_pi; X0.y *= inv_sqrt_pi;
        X1.x *= inv_sqrt_pi; X1.y *= inv_sqrt_pi;

        // x_hat_ri[b][n][t][c] -> flat b*2048 + n*4 + t*2 + c
        float4* xo = (float4*)(out + (size_t)b * 2048 + (size_t)n * 4);
        *xo = make_float4((float)X0.x, (float)X0.y, (float)X1.x, (float)X1.y);

        // nearest-QAM index per axis (argmin tie -> lower index, hence <=)
        const double bnd = 0.6324555320336759; // 2/sqrt(10)
        auto qi = [&](double v) -> int {
            return (v <= -bnd) ? 0 : (v <= 0.0) ? 1 : (v <= bnd) ? 2 : 3;
        };
        int vre0 = qi(X0.x), vim0 = qi(X0.y);
        int vre1 = qi(X1.x), vim1 = qi(X1.y);

        // b_hat[b][t][n*4+m] at base B*2048
        size_t bbase = (size_t)B * 2048;
        float4* b0 = (float4*)(out + bbase + ((size_t)b * 2 + 0) * 2048 + (size_t)n * 4);
        *b0 = make_float4((float)(vre0 & 1), (float)((vre0 >> 1) & 1),
                          (float)(vim0 & 1), (float)((vim0 >> 1) & 1));
        float4* b1 = (float4*)(out + bbase + ((size_t)b * 2 + 1) * 2048 + (size_t)n * 4);
        *b1 = make_float4((float)(vre1 & 1), (float)((vre1 >> 1) & 1),
                          (float)(vim1 & 1), (float)((vim1 >> 1) & 1));
    }
}

} // namespace

extern "C" void kernel_launch(void* const* d_in, const int* in_sizes, int n_in,
                              void* d_out, int out_size, void* d_ws, size_t ws_size,
                              hipStream_t stream) {
    const float* y_data = (const float*)d_in[0];
    const float* y_ls   = (const float*)d_in[1];
    const int*   x_idx  = (const int*)d_in[2];
    float* out = (float*)d_out;

    int B = in_sizes[0] / (2 * NTOT * 2);   // batch from flat input size
    ofdm_mimo_kernel<<<B, 512, 0, stream>>>(y_data, y_ls, x_idx, out, B);
}

// Round 2
// 52.461 us; speedup vs baseline: 1.1569x; 1.1569x over previous
//
#include <hip/hip_runtime.h>
#include <math.h>

namespace {

constexpr int NSC  = 512;   // subcarriers
constexpr int CP   = 7;     // cyclic prefix
constexpr int NTOT = 519;   // N + CP

// pad every 32 floats by 1 to break power-of-2 stride bank conflicts
__device__ __forceinline__ int padidx(int x) { return x + (x >> 5); }

struct cd { double x, y; };
__device__ __forceinline__ cd cmuld(cd a, cd b) { return {a.x*b.x - a.y*b.y, a.x*b.y + a.y*b.x}; }
__device__ __forceinline__ cd csubd(cd a, cd b) { return {a.x - b.x, a.y - b.y}; }
__device__ __forceinline__ cd cdivd(cd a, cd b) {
    double d = b.x*b.x + b.y*b.y;
    return {(a.x*b.x + a.y*b.y) / d, (a.y*b.x - a.x*b.y) / d};
}

__global__ __launch_bounds__(512) void ofdm_mimo_kernel(
    const float* __restrict__ y_data,
    const float* __restrict__ y_ls,
    const int*   __restrict__ x_idx,
    float*       __restrict__ out,
    int B)
{
    // 512 floats -> 528 padded slots
    __shared__ float bufr[4][528];        // 0: data r0, 1: data r1, 2: ls r0, 3: ls r1
    __shared__ float bufi[4][528];
    __shared__ float twr[264];            // 256 twiddles, padded
    __shared__ float twi[264];
    __shared__ float2 pil[2][2][NSC / 2]; // [tx][rx][pilot]

    const int b   = blockIdx.x;
    const int tid = threadIdx.x;

    const float data_scale = 1.0f / 512.0f;
    const float ls_scale   = (float)(1.0 / (512.0 * 0.22627416997969522)); // 1/(N*sqrt(pi_p))

    // ---- load CP-stripped samples, bit-reversed, with scale folded in ----
    #pragma unroll
    for (int e = tid; e < 4 * NSC; e += 512) {
        int q = e >> 9;          // which of the 4 signals
        int i = e & (NSC - 1);   // time index within the 512-sample window
        int r = q & 1;
        const float* src = (q < 2) ? y_data : y_ls;
        float sc = (q < 2) ? data_scale : ls_scale;
        size_t off = ((size_t)(b * 2 + r) * NTOT + CP + i) * 2;
        float re = src[off]     * sc;
        float im = src[off + 1] * sc;
        int rev = (int)(__brev((unsigned)i) >> 23);   // 9-bit reversal
        int p = padidx(rev);
        bufr[q][p] = re;
        bufi[q][p] = im;
    }
    if (tid < 256) {
        float s, c;
        __sincosf(-2.0f * (float)M_PI * (float)tid / 512.0f, &s, &c);
        int p = padidx(tid);
        twr[p] = c;
        twi[p] = s;
    }
    __syncthreads();

    // ---- 9 radix-2 DIT stages, 4 FFTs concurrently ----
    for (int s = 0; s < 9; ++s) {
        int half = 1 << s;
        #pragma unroll
        for (int j2 = tid; j2 < 1024; j2 += 512) {
            int q  = j2 >> 8;        // FFT id
            int jj = j2 & 255;       // butterfly id within FFT
            int g  = jj >> s;        // group
            int k  = jj & (half - 1);
            int i0 = (g << (s + 1)) + k;
            int i1 = i0 + half;
            int p0 = padidx(i0);
            int p1 = padidx(i1);
            int tp = padidx(k << (8 - s));
            float wr = twr[tp], wi = twi[tp];
            float ar = bufr[q][p0], ai = bufi[q][p0];
            float br = bufr[q][p1], bi = bufi[q][p1];
            float tr = wr * br - wi * bi;
            float ti = wr * bi + wi * br;
            bufr[q][p0] = ar + tr;
            bufi[q][p0] = ai + ti;
            bufr[q][p1] = ar - tr;
            bufi[q][p1] = ai - ti;
        }
        __syncthreads();
    }

    // ---- comb pilot LS estimates: pil[t][r][k] = Y_l[r][t+2k] / x_ls[t][t+2k] ----
    const float lev[4] = {-0.9486832980505138f, -0.31622776601683794f,
                           0.31622776601683794f, 0.9486832980505138f};
    #pragma unroll
    for (int p = tid; p < 1024; p += 512) {
        int t = p >> 9;
        int r = (p >> 8) & 1;
        int k = p & 255;
        int comb = t + 2 * k;
        int pc = padidx(comb);
        int idx = x_idx[((size_t)b * 2 + t) * NSC + comb];
        float xr = lev[idx & 3];
        float xi = lev[(idx >> 2) & 3];
        float ylr = bufr[2 + r][pc];
        float yli = bufi[2 + r][pc];
        float inv = 1.0f / (xr * xr + xi * xi);
        pil[t][r][k] = make_float2((ylr * xr + yli * xi) * inv,
                                   (yli * xr - ylr * xi) * inv);
    }
    __syncthreads();

    // ---- per-subcarrier: interp H, 2x2 solve (fp64 Cramer), demap ----
    {
        const int n = tid;
        cd H[2][2];
        #pragma unroll
        for (int r = 0; r < 2; ++r) {
            // t = 0: pilots at even n (plus copy at n=511)
            float2 h0;
            if ((n & 1) == 0) {
                h0 = pil[0][r][n >> 1];
            } else if (n == NSC - 1) {
                h0 = pil[0][r][255];
            } else {
                float2 a = pil[0][r][n >> 1];
                float2 c = pil[0][r][(n >> 1) + 1];
                h0 = make_float2(0.5f * (a.x + c.x), 0.5f * (a.y + c.y));
            }
            // t = 1: pilots at odd n (plus copy at n=0)
            float2 h1;
            if (n & 1) {
                h1 = pil[1][r][n >> 1];
            } else if (n == 0) {
                h1 = pil[1][r][0];
            } else {
                float2 a = pil[1][r][(n >> 1) - 1];
                float2 c = pil[1][r][n >> 1];
                h1 = make_float2(0.5f * (a.x + c.x), 0.5f * (a.y + c.y));
            }
            H[r][0] = {(double)h0.x, (double)h0.y};
            H[r][1] = {(double)h1.x, (double)h1.y};
        }
        int pn = padidx(n);
        cd Y0 = {(double)bufr[0][pn], (double)bufi[0][pn]};
        cd Y1 = {(double)bufr[1][pn], (double)bufi[1][pn]};

        cd det = csubd(cmuld(H[0][0], H[1][1]), cmuld(H[0][1], H[1][0]));
        cd X0  = cdivd(csubd(cmuld(H[1][1], Y0), cmuld(H[0][1], Y1)), det);
        cd X1  = cdivd(csubd(cmuld(H[0][0], Y1), cmuld(H[1][0], Y0)), det);
        const double inv_sqrt_pi = 1.0 / 0.22627416997969522;
        X0.x *= inv_sqrt_pi; X0.y *= inv_sqrt_pi;
        X1.x *= inv_sqrt_pi; X1.y *= inv_sqrt_pi;

        // x_hat_ri[b][n][t][c] -> flat b*2048 + n*4 + t*2 + c
        float4* xo = (float4*)(out + (size_t)b * 2048 + (size_t)n * 4);
        *xo = make_float4((float)X0.x, (float)X0.y, (float)X1.x, (float)X1.y);

        // nearest-QAM index per axis (argmin tie -> lower index, hence <=)
        const double bnd = 0.6324555320336759; // 2/sqrt(10)
        auto qi = [&](double v) -> int {
            return (v <= -bnd) ? 0 : (v <= 0.0) ? 1 : (v <= bnd) ? 2 : 3;
        };
        int vre0 = qi(X0.x), vim0 = qi(X0.y);
        int vre1 = qi(X1.x), vim1 = qi(X1.y);

        // b_hat[b][t][n*4+m] at base B*2048
        size_t bbase = (size_t)B * 2048;
        float4* b0 = (float4*)(out + bbase + ((size_t)b * 2 + 0) * 2048 + (size_t)n * 4);
        *b0 = make_float4((float)(vre0 & 1), (float)((vre0 >> 1) & 1),
                          (float)(vim0 & 1), (float)((vim0 >> 1) & 1));
        float4* b1 = (float4*)(out + bbase + ((size_t)b * 2 + 1) * 2048 + (size_t)n * 4);
        *b1 = make_float4((float)(vre1 & 1), (float)((vre1 >> 1) & 1),
                          (float)(vim1 & 1), (float)((vim1 >> 1) & 1));
    }
}

} // namespace

extern "C" void kernel_launch(void* const* d_in, const int* in_sizes, int n_in,
                              void* d_out, int out_size, void* d_ws, size_t ws_size,
                              hipStream_t stream) {
    const float* y_data = (const float*)d_in[0];
    const float* y_ls   = (const float*)d_in[1];
    const int*   x_idx  = (const int*)d_in[2];
    float* out = (float*)d_out;

    int B = in_sizes[0] / (2 * NTOT * 2);   // batch from flat input size
    ofdm_mimo_kernel<<<B, 512, 0, stream>>>(y_data, y_ls, x_idx, out, B);
}

// Round 3
// 40.885 us; speedup vs baseline: 1.4845x; 1.2831x over previous
//
#include <hip/hip_runtime.h>
#include <math.h>

namespace {

constexpr int NSC  = 512;   // subcarriers
constexpr int CP   = 7;     // cyclic prefix
constexpr int NTOT = 519;   // N + CP

// pad every 32 floats by 1 to break power-of-2 stride bank conflicts
__device__ __forceinline__ int padidx(int x) { return x + (x >> 5); }

struct cf { float x, y; };
__device__ __forceinline__ cf cadd(cf a, cf b) { return {a.x + b.x, a.y + b.y}; }
__device__ __forceinline__ cf csub(cf a, cf b) { return {a.x - b.x, a.y - b.y}; }
__device__ __forceinline__ cf cmul(cf a, cf b) { return {a.x*b.x - a.y*b.y, a.x*b.y + a.y*b.x}; }
__device__ __forceinline__ cf mni(cf a) { return {a.y, -a.x}; }   // multiply by -i

// natural-order in/out 8-point DFT: out[k] = sum_j in[j] W8^{jk}, W8 = e^{-2pi i/8}
__device__ __forceinline__ void fft8(cf a[8]) {
    const float s = 0.70710678118654752f;
    cf b0 = a[0], b1 = a[4], b2 = a[2], b3 = a[6];
    cf b4 = a[1], b5 = a[5], b6 = a[3], b7 = a[7];
    cf c0 = cadd(b0, b1), c1 = csub(b0, b1);
    cf c2 = cadd(b2, b3), c3 = csub(b2, b3);
    cf c4 = cadd(b4, b5), c5 = csub(b4, b5);
    cf c6 = cadd(b6, b7), c7 = csub(b6, b7);
    cf d0 = cadd(c0, c2), d2 = csub(c0, c2);
    cf d1 = cadd(c1, mni(c3)), d3 = csub(c1, mni(c3));
    cf d4 = cadd(c4, c6), d6 = csub(c4, c6);
    cf d5 = cadd(c5, mni(c7)), d7 = csub(c5, mni(c7));
    cf e5 = { s * (d5.x + d5.y), s * (d5.y - d5.x) };   // W8^1 * d5
    cf e6 = mni(d6);                                     // W8^2 * d6
    cf e7 = { s * (d7.y - d7.x), -s * (d7.x + d7.y) };   // W8^3 * d7
    a[0] = cadd(d0, d4); a[4] = csub(d0, d4);
    a[1] = cadd(d1, e5); a[5] = csub(d1, e5);
    a[2] = cadd(d2, e6); a[6] = csub(d2, e6);
    a[3] = cadd(d3, e7); a[7] = csub(d3, e7);
}

struct cd { double x, y; };
__device__ __forceinline__ cd cmuld(cd a, cd b) { return {a.x*b.x - a.y*b.y, a.x*b.y + a.y*b.x}; }
__device__ __forceinline__ cd csubd(cd a, cd b) { return {a.x - b.x, a.y - b.y}; }
__device__ __forceinline__ cd cdivd(cd a, cd b) {
    double d = b.x*b.x + b.y*b.y;
    return {(a.x*b.x + a.y*b.y) / d, (a.y*b.x - a.x*b.y) / d};
}

__global__ __launch_bounds__(256) void ofdm_mimo_kernel(
    const float* __restrict__ y_data,
    const float* __restrict__ y_ls,
    const int*   __restrict__ x_idx,
    float*       __restrict__ out,
    int B)
{
    // single reused scratch: T1 layout, then T2 layout, then final spectra
    __shared__ float sr[4][528];
    __shared__ float si[4][528];
    __shared__ float2 pil[2][2][NSC / 2]; // [tx][rx][pilot]

    const int b   = blockIdx.x;
    const int tid = threadIdx.x;
    const int q   = tid >> 6;   // wave id = signal id (0,1: data r0,r1; 2,3: ls r0,r1)
    const int t   = tid & 63;   // lane within the FFT

    const float data_scale = 1.0f / 512.0f;
    const float ls_scale   = (float)(1.0 / (512.0 * 0.22627416997969522)); // 1/(N*sqrt(pi_p))

    // ---- stage 1: load x[t + 64*n2] (coalesced float2), fft8 over n2 -> k0 ----
    const int r = q & 1;
    const float* srcp = (q < 2) ? y_data : y_ls;
    const float sc = (q < 2) ? data_scale : ls_scale;
    const float2* xin = (const float2*)(srcp + ((size_t)(b * 2 + r) * NTOT + CP) * 2);

    cf a[8];
    #pragma unroll
    for (int n2 = 0; n2 < 8; ++n2) {
        float2 v = xin[t + 64 * n2];
        a[n2] = { v.x * sc, v.y * sc };
    }
    fft8(a);   // a[k0]

    // twiddle W_64^{n1*k0}, n1 = t>>3
    {
        const int n1 = t >> 3;
        const float w64 = -6.2831853071795864769f / 64.0f;
        #pragma unroll
        for (int k0 = 1; k0 < 8; ++k0) {
            float sn, cs;
            __sincosf(w64 * (float)(n1 * k0), &sn, &cs);
            a[k0] = cmul(a[k0], {cs, sn});
        }
    }
    // T1 write: addr = t*8 + k0  (== n1*64 + n0*8 + k0)
    #pragma unroll
    for (int k0 = 0; k0 < 8; ++k0) {
        int p = padidx(t * 8 + k0);
        sr[q][p] = a[k0].x;
        si[q][p] = a[k0].y;
    }
    __syncthreads();

    // ---- stage 2: (n0,k0) = (t&7, t>>3); read A'[n0,n1,k0] over n1 ----
    #pragma unroll
    for (int n1 = 0; n1 < 8; ++n1) {
        int p = padidx(n1 * 64 + (t & 7) * 8 + (t >> 3));
        a[n1] = { sr[q][p], si[q][p] };
    }
    __syncthreads();           // all T1 reads done before T2 writes reuse buffer
    fft8(a);   // a[k1]

    // twiddle W_512^{n0*(k0+8*k1)}
    {
        const int n0 = t & 7, k0 = t >> 3;
        const float w512 = -6.2831853071795864769f / 512.0f;
        #pragma unroll
        for (int k1 = 0; k1 < 8; ++k1) {
            float sn, cs;
            __sincosf(w512 * (float)(n0 * (k0 + 8 * k1)), &sn, &cs);
            a[k1] = cmul(a[k1], {cs, sn});
        }
    }
    // T2 write: addr = n0*64 + k0*8 + k1
    #pragma unroll
    for (int k1 = 0; k1 < 8; ++k1) {
        int p = padidx((t & 7) * 64 + (t >> 3) * 8 + k1);
        sr[q][p] = a[k1].x;
        si[q][p] = a[k1].y;
    }
    __syncthreads();

    // ---- stage 3: (k0,k1) = (t>>3, t&7); read B'[n0,k0,k1] over n0 ----
    #pragma unroll
    for (int n0 = 0; n0 < 8; ++n0) {
        int p = padidx(n0 * 64 + (t >> 3) * 8 + (t & 7));
        a[n0] = { sr[q][p], si[q][p] };
    }
    __syncthreads();           // all T2 reads done before final writes reuse buffer
    fft8(a);   // a[k2]

    // final write: X[k0 + 8*k1 + 64*k2]
    #pragma unroll
    for (int k2 = 0; k2 < 8; ++k2) {
        int p = padidx((t >> 3) + 8 * (t & 7) + 64 * k2);
        sr[q][p] = a[k2].x;
        si[q][p] = a[k2].y;
    }
    __syncthreads();

    // ---- comb pilot LS estimates: pil[tx][rx][k] = Y_l[rx][tx+2k] / x_ls[tx][tx+2k] ----
    const float lev[4] = {-0.9486832980505138f, -0.31622776601683794f,
                           0.31622776601683794f, 0.9486832980505138f};
    #pragma unroll
    for (int pi = tid; pi < 1024; pi += 256) {
        int tt = pi >> 9;
        int rr = (pi >> 8) & 1;
        int k  = pi & 255;
        int comb = tt + 2 * k;
        int pc = padidx(comb);
        int idx = x_idx[((size_t)b * 2 + tt) * NSC + comb];
        float xr = lev[idx & 3];
        float xi = lev[(idx >> 2) & 3];
        float ylr = sr[2 + rr][pc];
        float yli = si[2 + rr][pc];
        float inv = 1.0f / (xr * xr + xi * xi);
        pil[tt][rr][k] = make_float2((ylr * xr + yli * xi) * inv,
                                     (yli * xr - ylr * xi) * inv);
    }
    __syncthreads();

    // ---- per-subcarrier: interp H, 2x2 solve (fp64 Cramer), demap ----
    #pragma unroll
    for (int ni = 0; ni < 2; ++ni) {
        const int n = tid + 256 * ni;
        cd H[2][2];
        #pragma unroll
        for (int rr = 0; rr < 2; ++rr) {
            // t = 0: pilots at even n (plus copy at n=511)
            float2 h0;
            if ((n & 1) == 0) {
                h0 = pil[0][rr][n >> 1];
            } else if (n == NSC - 1) {
                h0 = pil[0][rr][255];
            } else {
                float2 aa = pil[0][rr][n >> 1];
                float2 cc = pil[0][rr][(n >> 1) + 1];
                h0 = make_float2(0.5f * (aa.x + cc.x), 0.5f * (aa.y + cc.y));
            }
            // t = 1: pilots at odd n (plus copy at n=0)
            float2 h1;
            if (n & 1) {
                h1 = pil[1][rr][n >> 1];
            } else if (n == 0) {
                h1 = pil[1][rr][0];
            } else {
                float2 aa = pil[1][rr][(n >> 1) - 1];
                float2 cc = pil[1][rr][n >> 1];
                h1 = make_float2(0.5f * (aa.x + cc.x), 0.5f * (aa.y + cc.y));
            }
            H[rr][0] = {(double)h0.x, (double)h0.y};
            H[rr][1] = {(double)h1.x, (double)h1.y};
        }
        int pn = padidx(n);
        cd Y0 = {(double)sr[0][pn], (double)si[0][pn]};
        cd Y1 = {(double)sr[1][pn], (double)si[1][pn]};

        cd det = csubd(cmuld(H[0][0], H[1][1]), cmuld(H[0][1], H[1][0]));
        cd X0  = cdivd(csubd(cmuld(H[1][1], Y0), cmuld(H[0][1], Y1)), det);
        cd X1  = cdivd(csubd(cmuld(H[0][0], Y1), cmuld(H[1][0], Y0)), det);
        const double inv_sqrt_pi = 1.0 / 0.22627416997969522;
        X0.x *= inv_sqrt_pi; X0.y *= inv_sqrt_pi;
        X1.x *= inv_sqrt_pi; X1.y *= inv_sqrt_pi;

        // x_hat_ri[b][n][t][c] -> flat b*2048 + n*4 + t*2 + c
        float4* xo = (float4*)(out + (size_t)b * 2048 + (size_t)n * 4);
        *xo = make_float4((float)X0.x, (float)X0.y, (float)X1.x, (float)X1.y);

        // nearest-QAM index per axis (argmin tie -> lower index, hence <=)
        const double bnd = 0.6324555320336759; // 2/sqrt(10)
        auto qi = [&](double v) -> int {
            return (v <= -bnd) ? 0 : (v <= 0.0) ? 1 : (v <= bnd) ? 2 : 3;
        };
        int vre0 = qi(X0.x), vim0 = qi(X0.y);
        int vre1 = qi(X1.x), vim1 = qi(X1.y);

        // b_hat[b][t][n*4+m] at base B*2048
        size_t bbase = (size_t)B * 2048;
        float4* b0 = (float4*)(out + bbase + ((size_t)b * 2 + 0) * 2048 + (size_t)n * 4);
        *b0 = make_float4((float)(vre0 & 1), (float)((vre0 >> 1) & 1),
                          (float)(vim0 & 1), (float)((vim0 >> 1) & 1));
        float4* b1 = (float4*)(out + bbase + ((size_t)b * 2 + 1) * 2048 + (size_t)n * 4);
        *b1 = make_float4((float)(vre1 & 1), (float)((vre1 >> 1) & 1),
                          (float)(vim1 & 1), (float)((vim1 >> 1) & 1));
    }
}

} // namespace

extern "C" void kernel_launch(void* const* d_in, const int* in_sizes, int n_in,
                              void* d_out, int out_size, void* d_ws, size_t ws_size,
                              hipStream_t stream) {
    const float* y_data = (const float*)d_in[0];
    const float* y_ls   = (const float*)d_in[1];
    const int*   x_idx  = (const int*)d_in[2];
    float* out = (float*)d_out;

    int B = in_sizes[0] / (2 * NTOT * 2);   // batch from flat input size
    ofdm_mimo_kernel<<<B, 256, 0, stream>>>(y_data, y_ls, x_idx, out, B);
}

// Round 4
// 39.323 us; speedup vs baseline: 1.5435x; 1.0397x over previous
//
#include <hip/hip_runtime.h>
#include <math.h>

namespace {

constexpr int NSC  = 512;   // subcarriers
constexpr int CP   = 7;     // cyclic prefix
constexpr int NTOT = 519;   // N + CP

// pad every 32 floats by 1 to break power-of-2 stride bank conflicts
__device__ __forceinline__ int padidx(int x) { return x + (x >> 5); }

struct cf { float x, y; };
__device__ __forceinline__ cf cadd(cf a, cf b) { return {a.x + b.x, a.y + b.y}; }
__device__ __forceinline__ cf csub(cf a, cf b) { return {a.x - b.x, a.y - b.y}; }
__device__ __forceinline__ cf cmul(cf a, cf b) { return {a.x*b.x - a.y*b.y, a.x*b.y + a.y*b.x}; }
__device__ __forceinline__ cf mni(cf a) { return {a.y, -a.x}; }   // multiply by -i

// natural-order in/out 8-point DFT: out[k] = sum_j in[j] W8^{jk}, W8 = e^{-2pi i/8}
__device__ __forceinline__ void fft8(cf a[8]) {
    const float s = 0.70710678118654752f;
    cf b0 = a[0], b1 = a[4], b2 = a[2], b3 = a[6];
    cf b4 = a[1], b5 = a[5], b6 = a[3], b7 = a[7];
    cf c0 = cadd(b0, b1), c1 = csub(b0, b1);
    cf c2 = cadd(b2, b3), c3 = csub(b2, b3);
    cf c4 = cadd(b4, b5), c5 = csub(b4, b5);
    cf c6 = cadd(b6, b7), c7 = csub(b6, b7);
    cf d0 = cadd(c0, c2), d2 = csub(c0, c2);
    cf d1 = cadd(c1, mni(c3)), d3 = csub(c1, mni(c3));
    cf d4 = cadd(c4, c6), d6 = csub(c4, c6);
    cf d5 = cadd(c5, mni(c7)), d7 = csub(c5, mni(c7));
    cf e5 = { s * (d5.x + d5.y), s * (d5.y - d5.x) };   // W8^1 * d5
    cf e6 = mni(d6);                                     // W8^2 * d6
    cf e7 = { s * (d7.y - d7.x), -s * (d7.x + d7.y) };   // W8^3 * d7
    a[0] = cadd(d0, d4); a[4] = csub(d0, d4);
    a[1] = cadd(d1, e5); a[5] = csub(d1, e5);
    a[2] = cadd(d2, e6); a[6] = csub(d2, e6);
    a[3] = cadd(d3, e7); a[7] = csub(d3, e7);
}

struct cd { double x, y; };
__device__ __forceinline__ cd cmuld(cd a, cd b) { return {a.x*b.x - a.y*b.y, a.x*b.y + a.y*b.x}; }
__device__ __forceinline__ cd csubd(cd a, cd b) { return {a.x - b.x, a.y - b.y}; }
__device__ __forceinline__ cd cdivd(cd a, cd b) {
    double d = b.x*b.x + b.y*b.y;
    return {(a.x*b.x + a.y*b.y) / d, (a.y*b.x - a.x*b.y) / d};
}

__global__ __launch_bounds__(256, 8) void ofdm_mimo_kernel(
    const float* __restrict__ y_data,
    const float* __restrict__ y_ls,
    const int*   __restrict__ x_idx,
    float*       __restrict__ out,
    int B)
{
    // scratch: per-wave FFT workspace; after the FFTs, sr/si[2..3] are reused
    // to hold the pilot LS estimates (in place of a separate pil array).
    __shared__ float sr[4][528];
    __shared__ float si[4][528];

    const int b   = blockIdx.x;
    const int tid = threadIdx.x;
    const int q   = tid >> 6;   // wave id = signal id (0,1: data r0,r1; 2,3: ls r0,r1)
    const int t   = tid & 63;   // lane within the FFT

    // both Y and Y_l are scaled by 1/(N*sqrt(pi)) -- the 1/sqrt(pi) on the
    // data path is folded into the FFT input (solve is linear in Y).
    const float sc = (float)(1.0 / (512.0 * 0.22627416997969522));

    // ---- stage 1: load x[t + 64*n2] (coalesced float2), fft8 over n2 -> k0 ----
    const int r = q & 1;
    const float* srcp = (q < 2) ? y_data : y_ls;
    const float2* xin = (const float2*)(srcp + ((size_t)(b * 2 + r) * NTOT + CP) * 2);

    cf a[8];
    #pragma unroll
    for (int n2 = 0; n2 < 8; ++n2) {
        float2 v = xin[t + 64 * n2];
        a[n2] = { v.x * sc, v.y * sc };
    }
    fft8(a);   // a[k0]

    // twiddle W_64^{n1*k0}, n1 = t>>3
    {
        const int n1 = t >> 3;
        const float w64 = -6.2831853071795864769f / 64.0f;
        #pragma unroll
        for (int k0 = 1; k0 < 8; ++k0) {
            float sn, cs;
            __sincosf(w64 * (float)(n1 * k0), &sn, &cs);
            a[k0] = cmul(a[k0], {cs, sn});
        }
    }
    // T1 write: addr = t*8 + k0  (== n1*64 + n0*8 + k0)
    // NOTE: sr[q]/si[q] is touched ONLY by wave q during the FFT; per-wave DS
    // ops complete in order, so only a compiler fence is needed (no s_barrier).
    #pragma unroll
    for (int k0 = 0; k0 < 8; ++k0) {
        int p = padidx(t * 8 + k0);
        sr[q][p] = a[k0].x;
        si[q][p] = a[k0].y;
    }
    __builtin_amdgcn_wave_barrier();

    // ---- stage 2: (n0,k0) = (t&7, t>>3); read A'[n0,n1,k0] over n1 ----
    #pragma unroll
    for (int n1 = 0; n1 < 8; ++n1) {
        int p = padidx(n1 * 64 + (t & 7) * 8 + (t >> 3));
        a[n1] = { sr[q][p], si[q][p] };
    }
    __builtin_amdgcn_wave_barrier();
    fft8(a);   // a[k1]

    // twiddle W_512^{n0*(k0+8*k1)}
    {
        const int n0 = t & 7, k0 = t >> 3;
        const float w512 = -6.2831853071795864769f / 512.0f;
        #pragma unroll
        for (int k1 = 0; k1 < 8; ++k1) {
            float sn, cs;
            __sincosf(w512 * (float)(n0 * (k0 + 8 * k1)), &sn, &cs);
            a[k1] = cmul(a[k1], {cs, sn});
        }
    }
    // T2 write: addr = n0*64 + k0*8 + k1
    #pragma unroll
    for (int k1 = 0; k1 < 8; ++k1) {
        int p = padidx((t & 7) * 64 + (t >> 3) * 8 + k1);
        sr[q][p] = a[k1].x;
        si[q][p] = a[k1].y;
    }
    __builtin_amdgcn_wave_barrier();

    // ---- stage 3: (k0,k1) = (t>>3, t&7); read B'[n0,k0,k1] over n0 ----
    #pragma unroll
    for (int n0 = 0; n0 < 8; ++n0) {
        int p = padidx(n0 * 64 + (t >> 3) * 8 + (t & 7));
        a[n0] = { sr[q][p], si[q][p] };
    }
    __builtin_amdgcn_wave_barrier();
    fft8(a);   // a[k2]

    // final write: X[k0 + 8*k1 + 64*k2]
    #pragma unroll
    for (int k2 = 0; k2 < 8; ++k2) {
        int p = padidx((t >> 3) + 8 * (t & 7) + 64 * k2);
        sr[q][p] = a[k2].x;
        si[q][p] = a[k2].y;
    }
    __syncthreads();   // cross-wave: spectra now visible to all waves

    // ---- comb pilot LS: pil[tt][rr][k] = Y_l[rr][tt+2k] / x_ls[tt][tt+2k] ----
    // computed into registers, then stored IN PLACE into sr/si[2..3]:
    //   pil[tt][rr][k] -> sr[2+tt][padidx(rr*256+k)]
    const float lev[4] = {-0.9486832980505138f, -0.31622776601683794f,
                           0.31622776601683794f, 0.9486832980505138f};
    float pr[2][2], pim[2][2];   // [j][rr]
    #pragma unroll
    for (int j = 0; j < 2; ++j) {
        int u  = tid + 256 * j;   // 0..511 over (tt,k)
        int tt = u >> 8;
        int k  = u & 255;
        int comb = tt + 2 * k;
        int idx = x_idx[((size_t)(b * 2 + tt)) * NSC + comb];
        float xr = lev[idx & 3];
        float xi = lev[(idx >> 2) & 3];
        float inv = 1.0f / (xr * xr + xi * xi);
        int pc = padidx(comb);
        #pragma unroll
        for (int rr = 0; rr < 2; ++rr) {
            float ylr = sr[2 + rr][pc];
            float yli = si[2 + rr][pc];
            pr[j][rr]  = (ylr * xr + yli * xi) * inv;
            pim[j][rr] = (yli * xr - ylr * xi) * inv;
        }
    }
    __syncthreads();   // all LS-spectra reads done before overwrite
    #pragma unroll
    for (int j = 0; j < 2; ++j) {
        int u  = tid + 256 * j;
        int tt = u >> 8;
        int k  = u & 255;
        #pragma unroll
        for (int rr = 0; rr < 2; ++rr) {
            int p = padidx(rr * 256 + k);
            sr[2 + tt][p] = pr[j][rr];
            si[2 + tt][p] = pim[j][rr];
        }
    }
    __syncthreads();

    // ---- per-subcarrier: interp H, 2x2 solve (fp64 Cramer), demap ----
    #pragma unroll
    for (int ni = 0; ni < 2; ++ni) {
        const int n = tid + 256 * ni;
        // pilot accessors: P(tt, rr, k) = sr[2+tt][padidx(rr*256+k)]
        cd H[2][2];
        #pragma unroll
        for (int rr = 0; rr < 2; ++rr) {
            float2 h0, h1;
            // t = 0: pilots at even n (plus copy at n=511)
            if ((n & 1) == 0) {
                int p = padidx(rr * 256 + (n >> 1));
                h0 = make_float2(sr[2][p], si[2][p]);
            } else if (n == NSC - 1) {
                int p = padidx(rr * 256 + 255);
                h0 = make_float2(sr[2][p], si[2][p]);
            } else {
                int pa = padidx(rr * 256 + (n >> 1));
                int pb = padidx(rr * 256 + (n >> 1) + 1);
                h0 = make_float2(0.5f * (sr[2][pa] + sr[2][pb]),
                                 0.5f * (si[2][pa] + si[2][pb]));
            }
            // t = 1: pilots at odd n (plus copy at n=0)
            if (n & 1) {
                int p = padidx(rr * 256 + (n >> 1));
                h1 = make_float2(sr[3][p], si[3][p]);
            } else if (n == 0) {
                int p = padidx(rr * 256 + 0);
                h1 = make_float2(sr[3][p], si[3][p]);
            } else {
                int pa = padidx(rr * 256 + (n >> 1) - 1);
                int pb = padidx(rr * 256 + (n >> 1));
                h1 = make_float2(0.5f * (sr[3][pa] + sr[3][pb]),
                                 0.5f * (si[3][pa] + si[3][pb]));
            }
            H[rr][0] = {(double)h0.x, (double)h0.y};
            H[rr][1] = {(double)h1.x, (double)h1.y};
        }
        int pn = padidx(n);
        cd Y0 = {(double)sr[0][pn], (double)si[0][pn]};
        cd Y1 = {(double)sr[1][pn], (double)si[1][pn]};

        cd det = csubd(cmuld(H[0][0], H[1][1]), cmuld(H[0][1], H[1][0]));
        cd X0  = cdivd(csubd(cmuld(H[1][1], Y0), cmuld(H[0][1], Y1)), det);
        cd X1  = cdivd(csubd(cmuld(H[0][0], Y1), cmuld(H[1][0], Y0)), det);
        // (1/sqrt(pi) already folded into the data-FFT scale)

        // x_hat_ri[b][n][t][c] -> flat b*2048 + n*4 + t*2 + c
        float4* xo = (float4*)(out + (size_t)b * 2048 + (size_t)n * 4);
        *xo = make_float4((float)X0.x, (float)X0.y, (float)X1.x, (float)X1.y);

        // nearest-QAM index per axis (argmin tie -> lower index, hence <=)
        const double bnd = 0.6324555320336759; // 2/sqrt(10)
        auto qi = [&](double v) -> int {
            return (v <= -bnd) ? 0 : (v <= 0.0) ? 1 : (v <= bnd) ? 2 : 3;
        };
        int vre0 = qi(X0.x), vim0 = qi(X0.y);
        int vre1 = qi(X1.x), vim1 = qi(X1.y);

        // b_hat[b][t][n*4+m] at base B*2048
        size_t bbase = (size_t)B * 2048;
        float4* b0 = (float4*)(out + bbase + ((size_t)b * 2 + 0) * 2048 + (size_t)n * 4);
        *b0 = make_float4((float)(vre0 & 1), (float)((vre0 >> 1) & 1),
                          (float)(vim0 & 1), (float)((vim0 >> 1) & 1));
        float4* b1 = (float4*)(out + bbase + ((size_t)b * 2 + 1) * 2048 + (size_t)n * 4);
        *b1 = make_float4((float)(vre1 & 1), (float)((vre1 >> 1) & 1),
                          (float)(vim1 & 1), (float)((vim1 >> 1) & 1));
    }
}

} // namespace

extern "C" void kernel_launch(void* const* d_in, const int* in_sizes, int n_in,
                              void* d_out, int out_size, void* d_ws, size_t ws_size,
                              hipStream_t stream) {
    const float* y_data = (const float*)d_in[0];
    const float* y_ls   = (const float*)d_in[1];
    const int*   x_idx  = (const int*)d_in[2];
    float* out = (float*)d_out;

    int B = in_sizes[0] / (2 * NTOT * 2);   // batch from flat input size
    ofdm_mimo_kernel<<<B, 256, 0, stream>>>(y_data, y_ls, x_idx, out, B);
}

// Round 5
// 35.267 us; speedup vs baseline: 1.7210x; 1.1150x over previous
//
#include <hip/hip_runtime.h>

namespace {

constexpr int NSC  = 512;   // subcarriers
constexpr int CP   = 7;     // cyclic prefix
constexpr int NTOT = 519;   // N + CP

// pad every 16 float2 by 1 to break power-of-2 strides (keeps 8B alignment)
__device__ __forceinline__ int p2(int x) { return x + (x >> 4); }

struct cf { float x, y; };
__device__ __forceinline__ cf cadd(cf a, cf b) { return {a.x + b.x, a.y + b.y}; }
__device__ __forceinline__ cf csub(cf a, cf b) { return {a.x - b.x, a.y - b.y}; }
__device__ __forceinline__ cf cmul(cf a, cf b) { return {a.x*b.x - a.y*b.y, a.x*b.y + a.y*b.x}; }
__device__ __forceinline__ cf mni(cf a) { return {a.y, -a.x}; }   // multiply by -i

// natural-order in/out 8-point DFT: out[k] = sum_j in[j] W8^{jk}, W8 = e^{-2pi i/8}
__device__ __forceinline__ void fft8(cf a[8]) {
    const float s = 0.70710678118654752f;
    cf b0 = a[0], b1 = a[4], b2 = a[2], b3 = a[6];
    cf b4 = a[1], b5 = a[5], b6 = a[3], b7 = a[7];
    cf c0 = cadd(b0, b1), c1 = csub(b0, b1);
    cf c2 = cadd(b2, b3), c3 = csub(b2, b3);
    cf c4 = cadd(b4, b5), c5 = csub(b4, b5);
    cf c6 = cadd(b6, b7), c7 = csub(b6, b7);
    cf d0 = cadd(c0, c2), d2 = csub(c0, c2);
    cf d1 = cadd(c1, mni(c3)), d3 = csub(c1, mni(c3));
    cf d4 = cadd(c4, c6), d6 = csub(c4, c6);
    cf d5 = cadd(c5, mni(c7)), d7 = csub(c5, mni(c7));
    cf e5 = { s * (d5.x + d5.y), s * (d5.y - d5.x) };   // W8^1 * d5
    cf e6 = mni(d6);                                     // W8^2 * d6
    cf e7 = { s * (d7.y - d7.x), -s * (d7.x + d7.y) };   // W8^3 * d7
    a[0] = cadd(d0, d4); a[4] = csub(d0, d4);
    a[1] = cadd(d1, e5); a[5] = csub(d1, e5);
    a[2] = cadd(d2, e6); a[6] = csub(d2, e6);
    a[3] = cadd(d3, e7); a[7] = csub(d3, e7);
}

struct cd { double x, y; };
__device__ __forceinline__ cd cmuld(cd a, cd b) { return {a.x*b.x - a.y*b.y, a.x*b.y + a.y*b.x}; }
__device__ __forceinline__ cd csubd(cd a, cd b) { return {a.x - b.x, a.y - b.y}; }

__global__ __launch_bounds__(256, 8) void ofdm_mimo_kernel(
    const float* __restrict__ y_data,
    const float* __restrict__ y_ls,
    const int*   __restrict__ x_idx,
    float*       __restrict__ out,
    int B)
{
    // per-wave FFT workspace (float2, padded); after the FFTs, sb[2..3] are
    // reused in place for the pilot LS estimates: pil[tt][rr][k] -> sb[2+tt][p2(rr*256+k)]
    __shared__ cf sb[4][544];

    const int b   = blockIdx.x;
    const int tid = threadIdx.x;
    const int q   = tid >> 6;   // wave id = signal id (0,1: data r0,r1; 2,3: ls r0,r1)
    const int t   = tid & 63;   // lane within the FFT

    // both Y and Y_l scaled by 1/(N*sqrt(pi)) -- 1/sqrt(pi) on the data path
    // folded into the FFT input (solve is linear in Y).
    const float sc = (float)(1.0 / (512.0 * 0.22627416997969522));

    const float W64A  = -6.2831853071795864769f / 64.0f;
    const float W512A = -6.2831853071795864769f / 512.0f;

    // ---- stage 1: load x[t + 64*n2] (coalesced float2), fft8 over n2 -> k0 ----
    const int r = q & 1;
    const float* srcp = (q < 2) ? y_data : y_ls;
    const float2* xin = (const float2*)(srcp + ((size_t)(b * 2 + r) * NTOT + CP) * 2);

    cf a[8];
    #pragma unroll
    for (int n2 = 0; n2 < 8; ++n2) {
        float2 v = xin[t + 64 * n2];
        a[n2] = { v.x * sc, v.y * sc };
    }
    fft8(a);   // a[k0]

    // twiddle W_64^{n1*k0}: one sincos + power recurrence
    {
        const int n1 = t >> 3;
        float sn, cs;
        __sincosf(W64A * (float)n1, &sn, &cs);
        cf w1 = {cs, sn}, w = w1;
        #pragma unroll
        for (int k0 = 1; k0 < 8; ++k0) {
            a[k0] = cmul(a[k0], w);
            w = cmul(w, w1);
        }
    }
    // T1 write: addr = t*8 + k0  (== n1*64 + n0*8 + k0); wave-private buffer
    #pragma unroll
    for (int k0 = 0; k0 < 8; ++k0) sb[q][p2(t * 8 + k0)] = a[k0];
    __builtin_amdgcn_wave_barrier();

    // ---- stage 2: (n0,k0) = (t&7, t>>3); read A'[n0,n1,k0] over n1 ----
    #pragma unroll
    for (int n1 = 0; n1 < 8; ++n1)
        a[n1] = sb[q][p2(n1 * 64 + (t & 7) * 8 + (t >> 3))];
    __builtin_amdgcn_wave_barrier();
    fft8(a);   // a[k1]

    // twiddle W_512^{n0*(k0+8*k1)} = W512^{n0*k0} * (W64^{n0})^{k1}
    {
        const int n0 = t & 7, k0 = t >> 3;
        float sn, cs, sn2, cs2;
        __sincosf(W512A * (float)(n0 * k0), &sn, &cs);
        __sincosf(W64A * (float)n0, &sn2, &cs2);
        cf w = {cs, sn}, st = {cs2, sn2};
        #pragma unroll
        for (int k1 = 0; k1 < 8; ++k1) {
            a[k1] = cmul(a[k1], w);
            w = cmul(w, st);
        }
    }
    // T2 write: addr = n0*64 + k0*8 + k1
    #pragma unroll
    for (int k1 = 0; k1 < 8; ++k1)
        sb[q][p2((t & 7) * 64 + (t >> 3) * 8 + k1)] = a[k1];
    __builtin_amdgcn_wave_barrier();

    // ---- stage 3: (k0,k1) = (t>>3, t&7); read B'[n0,k0,k1] over n0 ----
    #pragma unroll
    for (int n0 = 0; n0 < 8; ++n0)
        a[n0] = sb[q][p2(n0 * 64 + (t >> 3) * 8 + (t & 7))];
    __builtin_amdgcn_wave_barrier();
    fft8(a);   // a[k2]

    // final write: X[k0 + 8*k1 + 64*k2]
    #pragma unroll
    for (int k2 = 0; k2 < 8; ++k2)
        sb[q][p2((t >> 3) + 8 * (t & 7) + 64 * k2)] = a[k2];
    __syncthreads();   // cross-wave: spectra visible to all waves

    // ---- comb pilot LS: pil[tt][rr][k] = Y_l[rr][tt+2k] / x_ls[tt][tt+2k] ----
    const float lev[4] = {-0.9486832980505138f, -0.31622776601683794f,
                           0.31622776601683794f, 0.9486832980505138f};
    cf pv[2][2];   // [j][rr]
    #pragma unroll
    for (int j = 0; j < 2; ++j) {
        int u  = tid + 256 * j;   // (tt = u>>8, k = u&255)
        int tt = u >> 8;
        int k  = u & 255;
        int comb = tt + 2 * k;
        int idx = x_idx[((size_t)(b * 2 + tt)) * NSC + comb];
        float xr = lev[idx & 3];
        float xi = lev[(idx >> 2) & 3];
        float inv = 1.0f / (xr * xr + xi * xi);
        #pragma unroll
        for (int rr = 0; rr < 2; ++rr) {
            cf yl = sb[2 + rr][p2(comb)];
            pv[j][rr] = { (yl.x * xr + yl.y * xi) * inv,
                          (yl.y * xr - yl.x * xi) * inv };
        }
    }
    __syncthreads();   // all LS-spectra reads done before overwrite
    #pragma unroll
    for (int j = 0; j < 2; ++j) {
        int u  = tid + 256 * j;
        int tt = u >> 8;
        int k  = u & 255;
        #pragma unroll
        for (int rr = 0; rr < 2; ++rr)
            sb[2 + tt][p2(rr * 256 + k)] = pv[j][rr];
    }
    __syncthreads();

    // ---- per-subcarrier: branchless interp H, 2x2 solve (fp64, 1 divide), demap ----
    #pragma unroll
    for (int ni = 0; ni < 2; ++ni) {
        const int n = tid + 256 * ni;
        const int kp = n >> 1;
        const int kR = (kp + 1 < 256) ? kp + 1 : 255;
        const int kL = (kp - 1 > 0) ? kp - 1 : 0;
        const float wA = (n & 1) ? 0.5f : 0.0f;   // t=0: exact at even n
        const float wB = (n & 1) ? 0.0f : 0.5f;   // t=1: exact at odd n

        cd H[2][2];
        #pragma unroll
        for (int rr = 0; rr < 2; ++rr) {
            cf L0 = sb[2][p2(rr * 256 + kp)];
            cf R0 = sb[2][p2(rr * 256 + kR)];
            cf h0 = { L0.x + wA * (R0.x - L0.x), L0.y + wA * (R0.y - L0.y) };
            cf R1 = sb[3][p2(rr * 256 + kp)];
            cf L1 = sb[3][p2(rr * 256 + kL)];
            cf h1 = { R1.x + wB * (L1.x - R1.x), R1.y + wB * (L1.y - R1.y) };
            H[rr][0] = {(double)h0.x, (double)h0.y};
            H[rr][1] = {(double)h1.x, (double)h1.y};
        }
        cf y0 = sb[0][p2(n)], y1 = sb[1][p2(n)];
        cd Y0 = {(double)y0.x, (double)y0.y};
        cd Y1 = {(double)y1.x, (double)y1.y};

        cd det  = csubd(cmuld(H[0][0], H[1][1]), cmuld(H[0][1], H[1][0]));
        cd num0 = csubd(cmuld(H[1][1], Y0), cmuld(H[0][1], Y1));
        cd num1 = csubd(cmuld(H[0][0], Y1), cmuld(H[1][0], Y0));
        double invden = 1.0 / (det.x * det.x + det.y * det.y);
        cd X0 = { (num0.x * det.x + num0.y * det.y) * invden,
                  (num0.y * det.x - num0.x * det.y) * invden };
        cd X1 = { (num1.x * det.x + num1.y * det.y) * invden,
                  (num1.y * det.x - num1.x * det.y) * invden };

        // x_hat_ri[b][n][t][c] -> flat b*2048 + n*4 + t*2 + c
        float4* xo = (float4*)(out + (size_t)b * 2048 + (size_t)n * 4);
        *xo = make_float4((float)X0.x, (float)X0.y, (float)X1.x, (float)X1.y);

        // nearest-QAM index per axis (argmin tie -> lower index, hence <=)
        const double bnd = 0.6324555320336759; // 2/sqrt(10)
        auto qi = [&](double v) -> int {
            return (v <= -bnd) ? 0 : (v <= 0.0) ? 1 : (v <= bnd) ? 2 : 3;
        };
        int vre0 = qi(X0.x), vim0 = qi(X0.y);
        int vre1 = qi(X1.x), vim1 = qi(X1.y);

        // b_hat[b][t][n*4+m] at base B*2048
        size_t bbase = (size_t)B * 2048;
        float4* b0 = (float4*)(out + bbase + ((size_t)b * 2 + 0) * 2048 + (size_t)n * 4);
        *b0 = make_float4((float)(vre0 & 1), (float)((vre0 >> 1) & 1),
                          (float)(vim0 & 1), (float)((vim0 >> 1) & 1));
        float4* b1 = (float4*)(out + bbase + ((size_t)b * 2 + 1) * 2048 + (size_t)n * 4);
        *b1 = make_float4((float)(vre1 & 1), (float)((vre1 >> 1) & 1),
                          (float)(vim1 & 1), (float)((vim1 >> 1) & 1));
    }
}

} // namespace

extern "C" void kernel_launch(void* const* d_in, const int* in_sizes, int n_in,
                              void* d_out, int out_size, void* d_ws, size_t ws_size,
                              hipStream_t stream) {
    const float* y_data = (const float*)d_in[0];
    const float* y_ls   = (const float*)d_in[1];
    const int*   x_idx  = (const int*)d_in[2];
    float* out = (float*)d_out;

    int B = in_sizes[0] / (2 * NTOT * 2);   // batch from flat input size
    ofdm_mimo_kernel<<<B, 256, 0, stream>>>(y_data, y_ls, x_idx, out, B);
}

// Round 6
// 33.794 us; speedup vs baseline: 1.7960x; 1.0436x over previous
//
#include <hip/hip_runtime.h>

namespace {

constexpr int NSC  = 512;   // subcarriers
constexpr int CP   = 7;     // cyclic prefix
constexpr int NTOT = 519;   // N + CP

// pad every 16 float2 by 1 to break power-of-2 strides (8B granularity)
__device__ __forceinline__ int p2(int x) { return x + (x >> 4); }
// pad every 16 float4 by 1 (16B granularity, keeps b128 alignment)
__device__ __forceinline__ int p4(int x) { return x + (x >> 4); }

struct cf { float x, y; };
__device__ __forceinline__ cf cadd(cf a, cf b) { return {a.x + b.x, a.y + b.y}; }
__device__ __forceinline__ cf csub(cf a, cf b) { return {a.x - b.x, a.y - b.y}; }
__device__ __forceinline__ cf cmul(cf a, cf b) { return {a.x*b.x - a.y*b.y, a.x*b.y + a.y*b.x}; }
__device__ __forceinline__ cf mni(cf a) { return {a.y, -a.x}; }   // multiply by -i

// natural-order in/out 8-point DFT: out[k] = sum_j in[j] W8^{jk}, W8 = e^{-2pi i/8}
__device__ __forceinline__ void fft8(cf a[8]) {
    const float s = 0.70710678118654752f;
    cf b0 = a[0], b1 = a[4], b2 = a[2], b3 = a[6];
    cf b4 = a[1], b5 = a[5], b6 = a[3], b7 = a[7];
    cf c0 = cadd(b0, b1), c1 = csub(b0, b1);
    cf c2 = cadd(b2, b3), c3 = csub(b2, b3);
    cf c4 = cadd(b4, b5), c5 = csub(b4, b5);
    cf c6 = cadd(b6, b7), c7 = csub(b6, b7);
    cf d0 = cadd(c0, c2), d2 = csub(c0, c2);
    cf d1 = cadd(c1, mni(c3)), d3 = csub(c1, mni(c3));
    cf d4 = cadd(c4, c6), d6 = csub(c4, c6);
    cf d5 = cadd(c5, mni(c7)), d7 = csub(c5, mni(c7));
    cf e5 = { s * (d5.x + d5.y), s * (d5.y - d5.x) };   // W8^1 * d5
    cf e6 = mni(d6);                                     // W8^2 * d6
    cf e7 = { s * (d7.y - d7.x), -s * (d7.x + d7.y) };   // W8^3 * d7
    a[0] = cadd(d0, d4); a[4] = csub(d0, d4);
    a[1] = cadd(d1, e5); a[5] = csub(d1, e5);
    a[2] = cadd(d2, e6); a[6] = csub(d2, e6);
    a[3] = cadd(d3, e7); a[7] = csub(d3, e7);
}

__global__ __launch_bounds__(256, 8) void ofdm_mimo_kernel(
    const float* __restrict__ y_data,
    const float* __restrict__ y_ls,
    const int*   __restrict__ x_idx,
    float*       __restrict__ out,
    int B)
{
    // per-wave FFT workspace (float2, padded). After the FFTs, the sb[2..3]
    // rows are reused IN PLACE (as float4) for the pilot LS estimates:
    //   pil[tt][k] = {rr0.re, rr0.im, rr1.re, rr1.im} at float4-slot p4(k).
    __shared__ cf sb[4][544];

    const int b   = blockIdx.x;
    const int tid = threadIdx.x;
    const int q   = tid >> 6;   // wave id = signal id (0,1: data r0,r1; 2,3: ls r0,r1)
    const int t   = tid & 63;   // lane within the FFT

    // both Y and Y_l scaled by 1/(N*sqrt(pi)) -- 1/sqrt(pi) on the data path
    // folded into the FFT input (solve is linear in Y).
    const float sc = (float)(1.0 / (512.0 * 0.22627416997969522));

    const float W64A  = -6.2831853071795864769f / 64.0f;
    const float W512A = -6.2831853071795864769f / 512.0f;

    // ---- prefetch pilot symbol factors (global loads issued before FFT) ----
    const float lev[4] = {-0.9486832980505138f, -0.31622776601683794f,
                           0.31622776601683794f, 0.9486832980505138f};
    float pxr[2], pxi[2], pinv[2];   // j = 0,1 -> (tt = j, k = tid&255)... see below
    #pragma unroll
    for (int j = 0; j < 2; ++j) {
        int u  = tid + 256 * j;            // tt = u>>8 == j (256 threads)
        int k  = u & 255;
        int comb = j + 2 * k;
        int idx = x_idx[((size_t)(b * 2 + j)) * NSC + comb];
        float xr = lev[idx & 3];
        float xi = lev[(idx >> 2) & 3];
        pxr[j] = xr; pxi[j] = xi;
        pinv[j] = 1.0f / (xr * xr + xi * xi);
    }

    // ---- stage 1: load x[t + 64*n2] (coalesced float2), fft8 over n2 -> k0 ----
    const int r = q & 1;
    const float* srcp = (q < 2) ? y_data : y_ls;
    const float2* xin = (const float2*)(srcp + ((size_t)(b * 2 + r) * NTOT + CP) * 2);

    cf a[8];
    #pragma unroll
    for (int n2 = 0; n2 < 8; ++n2) {
        float2 v = xin[t + 64 * n2];
        a[n2] = { v.x * sc, v.y * sc };
    }
    fft8(a);   // a[k0]

    // twiddle W_64^{n1*k0}: one sincos + power recurrence
    {
        const int n1 = t >> 3;
        float sn, cs;
        __sincosf(W64A * (float)n1, &sn, &cs);
        cf w1 = {cs, sn}, w = w1;
        #pragma unroll
        for (int k0 = 1; k0 < 8; ++k0) {
            a[k0] = cmul(a[k0], w);
            w = cmul(w, w1);
        }
    }
    // T1 write: addr = t*8 + k0; wave-private buffer -> wave barrier only
    #pragma unroll
    for (int k0 = 0; k0 < 8; ++k0) sb[q][p2(t * 8 + k0)] = a[k0];
    __builtin_amdgcn_wave_barrier();

    // ---- stage 2: (n0,k0) = (t&7, t>>3); read A'[n0,n1,k0] over n1 ----
    #pragma unroll
    for (int n1 = 0; n1 < 8; ++n1)
        a[n1] = sb[q][p2(n1 * 64 + (t & 7) * 8 + (t >> 3))];
    __builtin_amdgcn_wave_barrier();
    fft8(a);   // a[k1]

    // twiddle W_512^{n0*(k0+8*k1)} = W512^{n0*k0} * (W64^{n0})^{k1}
    {
        const int n0 = t & 7, k0 = t >> 3;
        float sn, cs, sn2, cs2;
        __sincosf(W512A * (float)(n0 * k0), &sn, &cs);
        __sincosf(W64A * (float)n0, &sn2, &cs2);
        cf w = {cs, sn}, st = {cs2, sn2};
        #pragma unroll
        for (int k1 = 0; k1 < 8; ++k1) {
            a[k1] = cmul(a[k1], w);
            w = cmul(w, st);
        }
    }
    // T2 write: addr = n0*64 + k0*8 + k1
    #pragma unroll
    for (int k1 = 0; k1 < 8; ++k1)
        sb[q][p2((t & 7) * 64 + (t >> 3) * 8 + k1)] = a[k1];
    __builtin_amdgcn_wave_barrier();

    // ---- stage 3: (k0,k1) = (t>>3, t&7); read B'[n0,k0,k1] over n0 ----
    #pragma unroll
    for (int n0 = 0; n0 < 8; ++n0)
        a[n0] = sb[q][p2(n0 * 64 + (t >> 3) * 8 + (t & 7))];
    __builtin_amdgcn_wave_barrier();
    fft8(a);   // a[k2]

    // final write: X[k0 + 8*k1 + 64*k2]
    #pragma unroll
    for (int k2 = 0; k2 < 8; ++k2)
        sb[q][p2((t >> 3) + 8 * (t & 7) + 64 * k2)] = a[k2];
    __syncthreads();   // cross-wave: spectra visible to all waves

    // ---- comb pilot LS: pil[tt][rr][k] = Y_l[rr][tt+2k] / x_ls[tt][tt+2k] ----
    float4 pout[2];   // [j] -> packed {rr0.re, rr0.im, rr1.re, rr1.im}
    #pragma unroll
    for (int j = 0; j < 2; ++j) {
        int k  = (tid + 256 * j) & 255;
        int comb = j + 2 * k;
        cf y0l = sb[2][p2(comb)];
        cf y1l = sb[3][p2(comb)];
        pout[j] = make_float4((y0l.x * pxr[j] + y0l.y * pxi[j]) * pinv[j],
                              (y0l.y * pxr[j] - y0l.x * pxi[j]) * pinv[j],
                              (y1l.x * pxr[j] + y1l.y * pxi[j]) * pinv[j],
                              (y1l.y * pxr[j] - y1l.x * pxi[j]) * pinv[j]);
    }
    __syncthreads();   // all LS-spectra reads done before in-place overwrite
    {
        float4* pilA = (float4*)sb[2];   // tt = 0
        float4* pilB = (float4*)sb[3];   // tt = 1
        int k = tid & 255;
        pilA[p4(k)] = pout[0];
        pilB[p4(k)] = pout[1];
    }
    __syncthreads();

    // ---- per-subcarrier: branchless interp H, fp32 Cramer solve, demap ----
    const float4* pilA = (const float4*)sb[2];
    const float4* pilB = (const float4*)sb[3];
    #pragma unroll
    for (int ni = 0; ni < 2; ++ni) {
        const int n = tid + 256 * ni;
        const int kp = n >> 1;
        const int kR = (kp + 1 < 256) ? kp + 1 : 255;
        const int kL = (kp - 1 > 0) ? kp - 1 : 0;
        const float wA = (n & 1) ? 0.5f : 0.0f;   // t=0 pilots exact at even n
        const float wB = (n & 1) ? 0.0f : 0.5f;   // t=1 pilots exact at odd n

        float4 L0 = pilA[p4(kp)];
        float4 R0 = pilA[p4(kR)];
        float4 R1 = pilB[p4(kp)];
        float4 L1 = pilB[p4(kL)];

        // H[rr][t]; float4 = {rr0.re, rr0.im, rr1.re, rr1.im}
        cf H00 = { L0.x + wA * (R0.x - L0.x), L0.y + wA * (R0.y - L0.y) };
        cf H10 = { L0.z + wA * (R0.z - L0.z), L0.w + wA * (R0.w - L0.w) };
        cf H01 = { R1.x + wB * (L1.x - R1.x), R1.y + wB * (L1.y - R1.y) };
        cf H11 = { R1.z + wB * (L1.z - R1.z), R1.w + wB * (L1.w - R1.w) };

        cf Y0 = sb[0][p2(n)];
        cf Y1 = sb[1][p2(n)];

        cf det  = csub(cmul(H00, H11), cmul(H01, H10));
        cf num0 = csub(cmul(H11, Y0), cmul(H01, Y1));
        cf num1 = csub(cmul(H00, Y1), cmul(H10, Y0));
        float invden = 1.0f / (det.x * det.x + det.y * det.y);
        float X0r = (num0.x * det.x + num0.y * det.y) * invden;
        float X0i = (num0.y * det.x - num0.x * det.y) * invden;
        float X1r = (num1.x * det.x + num1.y * det.y) * invden;
        float X1i = (num1.y * det.x - num1.x * det.y) * invden;

        // x_hat_ri[b][n][t][c] -> flat b*2048 + n*4 + t*2 + c
        float4* xo = (float4*)(out + (size_t)b * 2048 + (size_t)n * 4);
        *xo = make_float4(X0r, X0i, X1r, X1i);

        // nearest-QAM index per axis (argmin tie -> lower index, hence <=)
        const float bnd = 0.63245553203367587f; // 2/sqrt(10)
        auto qi = [&](float v) -> int {
            return (v <= -bnd) ? 0 : (v <= 0.0f) ? 1 : (v <= bnd) ? 2 : 3;
        };
        int vre0 = qi(X0r), vim0 = qi(X0i);
        int vre1 = qi(X1r), vim1 = qi(X1i);

        // b_hat[b][t][n*4+m] at base B*2048
        size_t bbase = (size_t)B * 2048;
        float4* b0 = (float4*)(out + bbase + ((size_t)b * 2 + 0) * 2048 + (size_t)n * 4);
        *b0 = make_float4((float)(vre0 & 1), (float)((vre0 >> 1) & 1),
                          (float)(vim0 & 1), (float)((vim0 >> 1) & 1));
        float4* b1 = (float4*)(out + bbase + ((size_t)b * 2 + 1) * 2048 + (size_t)n * 4);
        *b1 = make_float4((float)(vre1 & 1), (float)((vre1 >> 1) & 1),
                          (float)(vim1 & 1), (float)((vim1 >> 1) & 1));
    }
}

} // namespace

extern "C" void kernel_launch(void* const* d_in, const int* in_sizes, int n_in,
                              void* d_out, int out_size, void* d_ws, size_t ws_size,
                              hipStream_t stream) {
    const float* y_data = (const float*)d_in[0];
    const float* y_ls   = (const float*)d_in[1];
    const int*   x_idx  = (const int*)d_in[2];
    float* out = (float*)d_out;

    int B = in_sizes[0] / (2 * NTOT * 2);   // batch from flat input size
    ofdm_mimo_kernel<<<B, 256, 0, stream>>>(y_data, y_ls, x_idx, out, B);
}